// Round 3
// baseline (226.497 us; speedup 1.0000x reference)
//
#include <hip/hip_runtime.h>
#include <hip/hip_bf16.h>
#include <math.h>

// ---------------- problem constants ----------------
#define NANC   5184        // 24*24*9
#define NPOS   576         // 24*24
#define CIN    512
#define MIDC   24
#define KANC   9
#define IMGW   384.0f
#define IMGM1  383.0f
#define MINSZ  16.0f
#define THRESH 0.7f

// d_out float offsets (outputs concatenated flat in return order)
#define OFF_PROP 0           // proposals  N*4
#define OFF_CLS  20736       // cls_out    N*2
#define OFF_FILT 31104       // filtered   N*4
#define OFF_PK   51840       // probs_kept N
#define OFF_LBL  57024       // labels_kept N (int -> float)
#define OFF_KEEP 62208       // keep       N (bool -> float)

// NMS capacity (geometric valid count is exactly 808)
#define MCAP 896
#define GCAP 14              // MCAP/64
#define TOTW (64 * (GCAP*(GCAP+1)/2))   // 6720 triangular u64 words

// ---------------- ws byte offsets ----------------
#define WS_XT    0            // 294912 f   (x transposed: [pos][ic])
#define WS_WT    1179648      // 110592 f   (W transposed: [oc][k][ic])
#define WS_BOX   1622016      // N float4   clipped boxes x0,y0,x1,y1
#define WS_PROB  1953792      // N f        softmax prob of class 1
#define WS_KEYS  2036736      // 1024 u64   sort keys of valid anchors
#define WS_SIDX  2044928      // 1024 i32   sorted orig indices
#define WS_SBOX  2049024      // MCAP float4 sorted boxes
#define WS_MASK  2063360      // TOTW u64   triangular IoU mask
#define WS_CNT   2117120      // u32        valid counter

// ============ K0: transpose x and W_rpn, zero counter ============
__global__ __launch_bounds__(256) void k_prep(const float* __restrict__ x,
                                              const float* __restrict__ W,
                                              float* __restrict__ xt,
                                              float* __restrict__ Wt,
                                              unsigned* cnt) {
    int tid = blockIdx.x * 256 + threadIdx.x;
    if (tid == 0) *cnt = 0;
    const int TOT = CIN * NPOS + MIDC * CIN * 9;   // 294912 + 110592
    for (int idx = tid; idx < TOT; idx += gridDim.x * 256) {
        if (idx < CIN * NPOS) {
            int pos = idx >> 9, ic = idx & 511;       // xt[pos*512+ic]
            xt[idx] = x[ic * NPOS + pos];
        } else {
            int k = idx - CIN * NPOS;                 // Wt[(oc*9+kk)*512+ic]
            int ic = k & 511; int t = k >> 9;
            int oc = t / 9, kk = t % 9;
            Wt[k] = W[(oc * CIN + ic) * 9 + kk];
        }
    }
}

// ============ K1: conv3x3+relu + heads + decode + score ============
// 144 blocks, each handles 4 consecutive positions in one row (24%4==0).
__global__ __launch_bounds__(256) void k_main(
        const float* __restrict__ xt, const float* __restrict__ Wt,
        const float* __restrict__ brpn,
        const float* __restrict__ Wc, const float* __restrict__ bc,
        const float* __restrict__ Wr, const float* __restrict__ br,
        const float* __restrict__ anchors,
        float* __restrict__ out, float4* __restrict__ boxes,
        float* __restrict__ probs, unsigned long long* __restrict__ vkeys,
        unsigned* __restrict__ cnt) {
    const int tid = threadIdx.x;
    const int y = blockIdx.x / 6;
    const int xb = (blockIdx.x % 6) * 4;

    float acc[24][4];
    #pragma unroll
    for (int oc = 0; oc < 24; ++oc)
        #pragma unroll
        for (int p = 0; p < 4; ++p) acc[oc][p] = 0.f;

    for (int half = 0; half < 2; ++half) {
        const int ic = tid + half * 256;
        float xw[3][6];
        #pragma unroll
        for (int r = 0; r < 3; ++r) {
            int yy = y - 1 + r;
            #pragma unroll
            for (int c = 0; c < 6; ++c) {
                int xx = xb - 1 + c;
                bool in = (yy >= 0) & (yy < 24) & (xx >= 0) & (xx < 24);
                xw[r][c] = in ? xt[(yy * 24 + xx) * CIN + ic] : 0.f;
            }
        }
        const float* wp = Wt + ic;
        #pragma unroll
        for (int oc = 0; oc < 24; ++oc) {
            #pragma unroll
            for (int kk = 0; kk < 9; ++kk) {
                const int r = kk / 3, c = kk % 3;
                float wv = wp[(oc * 9 + kk) * CIN];
                #pragma unroll
                for (int p = 0; p < 4; ++p)
                    acc[oc][p] += wv * xw[r][c + p];
            }
        }
    }
    // butterfly reduce across the 64-lane wave
    #pragma unroll
    for (int oc = 0; oc < 24; ++oc)
        #pragma unroll
        for (int p = 0; p < 4; ++p) {
            float v = acc[oc][p];
            #pragma unroll
            for (int m = 1; m < 64; m <<= 1) v += __shfl_xor(v, m, 64);
            acc[oc][p] = v;
        }

    __shared__ float red[4][96];
    __shared__ float h_ld[4 * 24];
    __shared__ float cls_ld[4 * 18];
    __shared__ float reg_ld[4 * 36];
    const int wave = tid >> 6, lane = tid & 63;
    if (lane == 0) {
        #pragma unroll
        for (int oc = 0; oc < 24; ++oc)
            #pragma unroll
            for (int p = 0; p < 4; ++p) red[wave][oc * 4 + p] = acc[oc][p];
    }
    __syncthreads();
    if (tid < 96) {
        float s = red[0][tid] + red[1][tid] + red[2][tid] + red[3][tid];
        int oc = tid >> 2, p = tid & 3;
        h_ld[p * 24 + oc] = fmaxf(s + brpn[oc], 0.f);
    }
    __syncthreads();
    if (tid < 216) {    // 4 pos * 54 outputs (18 cls + 36 reg)
        int p = tid / 54, o = tid % 54;
        const float* hv = h_ld + p * 24;
        if (o < 18) {
            float s = bc[o];
            const float* w = Wc + o * 24;
            #pragma unroll
            for (int c = 0; c < 24; ++c) s += w[c] * hv[c];
            cls_ld[p * 18 + o] = s;
            out[OFF_CLS + (y * 24 + xb + p) * 18 + o] = s;
        } else {
            int o2 = o - 18;
            float s = br[o2];
            const float* w = Wr + o2 * 24;
            #pragma unroll
            for (int c = 0; c < 24; ++c) s += w[c] * hv[c];
            reg_ld[p * 36 + o2] = s;
        }
    }
    __syncthreads();
    if (tid < 36) {     // 4 pos * 9 anchors
        #pragma clang fp contract(off)
        int p = tid / 9, k = tid % 9;
        int n = (y * 24 + xb + p) * 9 + k;
        float ax = anchors[4 * n], ay = anchors[4 * n + 1];
        float aw = anchors[4 * n + 2], ah = anchors[4 * n + 3];
        float tx = reg_ld[p * 36 + 4 * k],     ty = reg_ld[p * 36 + 4 * k + 1];
        float tw = reg_ld[p * 36 + 4 * k + 2], th = reg_ld[p * 36 + 4 * k + 3];
        float px = ax + aw * tx, py = ay + ah * ty;
        float pw = aw * expf(tw), ph = ah * expf(th);
        out[OFF_PROP + 4 * n]     = px;
        out[OFF_PROP + 4 * n + 1] = py;
        out[OFF_PROP + 4 * n + 2] = pw;
        out[OFF_PROP + 4 * n + 3] = ph;
        // geometric validity straight from anchors (exact: all values are
        // multiples of 0.5, f32 arithmetic identical to numpy reference)
        float gx0 = ax - 0.5f * (aw - 1.f);
        float gy0 = ay - 0.5f * (ah - 1.f);
        float gx1 = aw + gx0 - 1.f;
        float gy1 = ah + gy0 - 1.f;
        bool geo_ok = (gx0 >= 0.f) & (gy0 >= 0.f) & (gx1 < IMGW) & (gy1 < IMGW);
        float x0 = px - 0.5f * (pw - 1.f);
        float y0 = py - 0.5f * (ph - 1.f);
        float x1 = pw + x0 - 1.f;
        float y1 = ph + y0 - 1.f;
        x0 = fminf(fmaxf(x0, 0.f), IMGM1);
        x1 = fminf(fmaxf(x1, 0.f), IMGM1);
        y0 = fminf(fmaxf(y0, 0.f), IMGM1);
        y1 = fminf(fmaxf(y1, 0.f), IMGM1);
        float wsb = x1 - x0 + 1.f, hsb = y1 - y0 + 1.f;
        float c0 = cls_ld[p * 18 + 2 * k], c1 = cls_ld[p * 18 + 2 * k + 1];
        float mx = fmaxf(c0, c1);
        float e0 = expf(c0 - mx), e1 = expf(c1 - mx);
        float pr = e1 / (e0 + e1);
        boxes[n] = make_float4(x0, y0, x1, y1);
        probs[n] = pr;
        bool valid = geo_ok && (wsb >= MINSZ) && (hsb >= MINSZ);
        if (valid) {
            unsigned pos = atomicAdd(cnt, 1u);
            unsigned u = __float_as_uint(pr);
            unsigned enc = u ^ ((u >> 31) ? 0xFFFFFFFFu : 0x80000000u); // ascending in value
            vkeys[pos] = ((unsigned long long)(~enc) << 32) | (unsigned)n; // asc sort => desc prob, tie: idx asc
        }
    }
}

// ============ K2: bitonic sort of <=1024 valid keys (1 block) ============
__global__ __launch_bounds__(512) void k_sort(const unsigned long long* __restrict__ vkeys,
                                              const unsigned* __restrict__ cnt,
                                              int* __restrict__ sidx,
                                              float4* __restrict__ sbox,
                                              const float4* __restrict__ boxes) {
    __shared__ unsigned long long keys[1024];
    const int t = threadIdx.x;
    unsigned Mc = *cnt; unsigned M = Mc < (unsigned)MCAP ? Mc : (unsigned)MCAP;
    for (int i = t; i < 1024; i += 512) keys[i] = (i < (int)M) ? vkeys[i] : ~0ULL;
    __syncthreads();
    for (int k = 2; k <= 1024; k <<= 1) {
        for (int j = k >> 1; j > 0; j >>= 1) {
            int lo = t & (j - 1);
            int i = ((t ^ lo) << 1) | lo;
            int pa = i | j;
            bool up = (i & k) == 0;
            unsigned long long a = keys[i], b = keys[pa];
            if ((a > b) == up) { keys[i] = b; keys[pa] = a; }
            __syncthreads();
        }
    }
    for (int i = t; i < (int)M; i += 512) {
        int n = (int)(keys[i] & 0xFFFFFFFFu);
        sidx[i] = n;
        sbox[i] = boxes[n];
    }
}

// ============ K3: triangular IoU>thresh bitmask ============
__global__ __launch_bounds__(256) void k_mask(const float4* __restrict__ sbox,
                                              const unsigned* __restrict__ cnt,
                                              unsigned long long* __restrict__ mask) {
    __shared__ float4 sb[MCAP];
    const int t = threadIdx.x;
    for (int i = t; i < MCAP; i += 256) sb[i] = sbox[i];
    __syncthreads();
    unsigned Mc = *cnt; unsigned M = Mc < (unsigned)MCAP ? Mc : (unsigned)MCAP;
    int widx = blockIdx.x * 256 + t;
    if (widx >= TOTW) return;
    // decode triangular word index -> (row i, column group gw)
    int g = 0, base = 0;
    while (g < GCAP - 1) {
        int nb = base + 64 * (GCAP - g);
        if (widx < nb) break;
        base = nb; ++g;
    }
    int rem = widx - base;
    int r = rem / (GCAP - g);
    int gw = g + rem % (GCAP - g);
    int i = g * 64 + r;
    if (i >= (int)M) return;       // row never read
    {
        #pragma clang fp contract(off)
        float4 bi = sb[i];
        float ai = (bi.z - bi.x + 1.f) * (bi.w - bi.y + 1.f);
        unsigned long long w = 0;
        #pragma unroll 4
        for (int b = 0; b < 64; ++b) {
            int j = gw * 64 + b;
            if (j > i) {
                float4 bj = sb[j];
                float iw = fminf(bi.z, bj.z) - fmaxf(bi.x, bj.x) + 1.f;
                float ih = fminf(bi.w, bj.w) - fmaxf(bi.y, bj.y) + 1.f;
                iw = fmaxf(iw, 0.f); ih = fmaxf(ih, 0.f);
                float inter = iw * ih;
                float aj = (bj.z - bj.x + 1.f) * (bj.w - bj.y + 1.f);
                float iou = inter / (ai + aj - inter);
                if (iou > THRESH) w |= 1ULL << b;
            }
        }
        mask[widx] = w;
    }
}

// ============ K4: serial greedy NMS (wave 0) + full output finalize ============
__global__ __launch_bounds__(1024) void k_nms(const unsigned long long* __restrict__ mask_g,
                                              const int* __restrict__ sidx_g,
                                              const unsigned* __restrict__ cnt,
                                              const float4* __restrict__ boxes,
                                              const float* __restrict__ probs,
                                              const int* __restrict__ labels,
                                              float* __restrict__ out) {
    __shared__ unsigned long long mk[TOTW];          // 52.5 KB
    __shared__ int sidx[MCAP];
    __shared__ unsigned long long keepm[81];         // keep bits in ORIGINAL index space
    __shared__ unsigned long long keeps[GCAP];       // keep bits in SORTED space
    const int t = threadIdx.x;
    unsigned Mc = *cnt; unsigned M = Mc < (unsigned)MCAP ? Mc : (unsigned)MCAP;
    for (int i = t; i < TOTW; i += 1024) mk[i] = mask_g[i];
    if (t < MCAP) sidx[t] = sidx_g[t];
    if (t < 81) keepm[t] = 0;
    if (t < GCAP) keeps[t] = 0;
    __syncthreads();
    if (t < 64) {                                    // wave 0: serial greedy pass
        unsigned long long remv = 0, kw = 0;         // lane w owns suppression word w
        const int lane = t;
        for (int i = 0; i < (int)M; ++i) {
            int g = i >> 6, r = i & 63;
            unsigned long long rg = __shfl(remv, g, 64);
            bool keep = !((rg >> r) & 1ULL);         // wave-uniform
            if (keep) {
                int rowbase = 64 * (GCAP * g - (g * (g - 1)) / 2) + r * (GCAP - g);
                if (lane >= g && lane < GCAP)
                    remv |= mk[rowbase + (lane - g)];
                kw |= 1ULL << r;
            }
            if (r == 63 || i == (int)M - 1) {
                if (lane == 0) keeps[g] = kw;
                kw = 0;
            }
        }
    }
    __syncthreads();
    if (t < (int)M) {
        if ((keeps[t >> 6] >> (t & 63)) & 1ULL) {
            int n = sidx[t];
            atomicOr(&keepm[n >> 6], 1ULL << (n & 63));
        }
    }
    __syncthreads();
    for (int n = t; n < NANC; n += 1024) {
        unsigned long long kb = (keepm[n >> 6] >> (n & 63)) & 1ULL;
        float kf = kb ? 1.f : 0.f;
        float4 b = boxes[n];
        float wsb = b.z - b.x + 1.f, hsb = b.w - b.y + 1.f;
        out[OFF_FILT + 4 * n]     = (b.x + 0.5f * (wsb - 1.f)) * kf;
        out[OFF_FILT + 4 * n + 1] = (b.y + 0.5f * (hsb - 1.f)) * kf;
        out[OFF_FILT + 4 * n + 2] = wsb * kf;
        out[OFF_FILT + 4 * n + 3] = hsb * kf;
        out[OFF_PK + n]  = probs[n] * kf;
        out[OFF_LBL + n] = kb ? (float)labels[n] : 0.f;
        out[OFF_KEEP + n] = kf;
    }
}

extern "C" void kernel_launch(void* const* d_in, const int* in_sizes, int n_in,
                              void* d_out, int out_size, void* d_ws, size_t ws_size,
                              hipStream_t stream) {
    const float* x        = (const float*)d_in[0];
    const int*   labels   = (const int*)d_in[1];
    const float* Wrpn     = (const float*)d_in[2];
    const float* brpn     = (const float*)d_in[3];
    const float* Wcls     = (const float*)d_in[4];
    const float* bcls     = (const float*)d_in[5];
    const float* Wreg     = (const float*)d_in[6];
    const float* breg     = (const float*)d_in[7];
    const float* anchors  = (const float*)d_in[8];
    float* out = (float*)d_out;
    char* ws = (char*)d_ws;

    float*  xt    = (float*)(ws + WS_XT);
    float*  Wt    = (float*)(ws + WS_WT);
    float4* boxes = (float4*)(ws + WS_BOX);
    float*  probs = (float*)(ws + WS_PROB);
    unsigned long long* vkeys = (unsigned long long*)(ws + WS_KEYS);
    int*    sidx  = (int*)(ws + WS_SIDX);
    float4* sbox  = (float4*)(ws + WS_SBOX);
    unsigned long long* mask = (unsigned long long*)(ws + WS_MASK);
    unsigned* cnt = (unsigned*)(ws + WS_CNT);

    k_prep<<<1584, 256, 0, stream>>>(x, Wrpn, xt, Wt, cnt);
    k_main<<<144, 256, 0, stream>>>(xt, Wt, brpn, Wcls, bcls, Wreg, breg,
                                    anchors, out, boxes, probs, vkeys, cnt);
    k_sort<<<1, 512, 0, stream>>>(vkeys, cnt, sidx, sbox, boxes);
    k_mask<<<27, 256, 0, stream>>>(sbox, cnt, mask);
    k_nms<<<1, 1024, 0, stream>>>(mask, sidx, cnt, boxes, probs, labels, out);
}

// Round 4
// 171.804 us; speedup vs baseline: 1.3183x; 1.3183x over previous
//
#include <hip/hip_runtime.h>
#include <hip/hip_bf16.h>
#include <math.h>

// ---------------- problem constants ----------------
#define NANC   5184        // 24*24*9
#define NPOS   576         // 24*24
#define CIN    512
#define MIDC   24
#define KANC   9
#define IMGW   384.0f
#define IMGM1  383.0f
#define MINSZ  16.0f
#define THRESH 0.7f

// d_out float offsets (outputs concatenated flat in return order)
#define OFF_PROP 0           // proposals  N*4
#define OFF_CLS  20736       // cls_out    N*2
#define OFF_FILT 31104       // filtered   N*4
#define OFF_PK   51840       // probs_kept N
#define OFF_LBL  57024       // labels_kept N (int -> float)
#define OFF_KEEP 62208       // keep       N (bool -> float)

// NMS capacity (geometric valid count is exactly 808)
#define MCAP 896
#define GCAP 14              // MCAP/64
#define TOTW (64 * (GCAP*(GCAP+1)/2))   // 6720 triangular u64 words

// ---------------- ws byte offsets ----------------
#define WS_XT    0            // 294912 f   (x transposed: [pos][ic])
#define WS_WT    1179648      // 110592 f   (W transposed: [oc][k][ic])
#define WS_BOX   1622016      // N float4   clipped boxes x0,y0,x1,y1
#define WS_PROB  1953792      // N f        softmax prob of class 1
#define WS_KEYS  2036736      // 1024 u64   sort keys of valid anchors
#define WS_SIDX  2044928      // 1024 i32   sorted orig indices
#define WS_SBOX  2049024      // MCAP float4 sorted boxes
#define WS_MASK  2063360      // TOTW u64   triangular IoU mask
#define WS_CNT   2117120      // u32        valid counter

// ============ K0: transpose x and W_rpn, zero counter ============
__global__ __launch_bounds__(256) void k_prep(const float* __restrict__ x,
                                              const float* __restrict__ W,
                                              float* __restrict__ xt,
                                              float* __restrict__ Wt,
                                              unsigned* cnt) {
    int tid = blockIdx.x * 256 + threadIdx.x;
    if (tid == 0) *cnt = 0;
    const int TOT = CIN * NPOS + MIDC * CIN * 9;   // 294912 + 110592
    for (int idx = tid; idx < TOT; idx += gridDim.x * 256) {
        if (idx < CIN * NPOS) {
            int pos = idx >> 9, ic = idx & 511;       // xt[pos*512+ic]
            xt[idx] = x[ic * NPOS + pos];
        } else {
            int k = idx - CIN * NPOS;                 // Wt[(oc*9+kk)*512+ic]
            int ic = k & 511; int t = k >> 9;
            int oc = t / 9, kk = t % 9;
            Wt[k] = W[(oc * CIN + ic) * 9 + kk];
        }
    }
}

// ============ K1: conv3x3+relu + heads + decode + score ============
// 144 blocks, each handles 4 consecutive positions in one row (24%4==0).
__global__ __launch_bounds__(256) void k_main(
        const float* __restrict__ xt, const float* __restrict__ Wt,
        const float* __restrict__ brpn,
        const float* __restrict__ Wc, const float* __restrict__ bc,
        const float* __restrict__ Wr, const float* __restrict__ br,
        const float* __restrict__ anchors,
        float* __restrict__ out, float4* __restrict__ boxes,
        float* __restrict__ probs, unsigned long long* __restrict__ vkeys,
        unsigned* __restrict__ cnt) {
    const int tid = threadIdx.x;
    const int y = blockIdx.x / 6;
    const int xb = (blockIdx.x % 6) * 4;

    float acc[24][4];
    #pragma unroll
    for (int oc = 0; oc < 24; ++oc)
        #pragma unroll
        for (int p = 0; p < 4; ++p) acc[oc][p] = 0.f;

    for (int half = 0; half < 2; ++half) {
        const int ic = tid + half * 256;
        float xw[3][6];
        #pragma unroll
        for (int r = 0; r < 3; ++r) {
            int yy = y - 1 + r;
            #pragma unroll
            for (int c = 0; c < 6; ++c) {
                int xx = xb - 1 + c;
                bool in = (yy >= 0) & (yy < 24) & (xx >= 0) & (xx < 24);
                xw[r][c] = in ? xt[(yy * 24 + xx) * CIN + ic] : 0.f;
            }
        }
        const float* wp = Wt + ic;
        #pragma unroll
        for (int oc = 0; oc < 24; ++oc) {
            #pragma unroll
            for (int kk = 0; kk < 9; ++kk) {
                const int r = kk / 3, c = kk % 3;
                float wv = wp[(oc * 9 + kk) * CIN];
                #pragma unroll
                for (int p = 0; p < 4; ++p)
                    acc[oc][p] += wv * xw[r][c + p];
            }
        }
    }
    // butterfly reduce across the 64-lane wave
    #pragma unroll
    for (int oc = 0; oc < 24; ++oc)
        #pragma unroll
        for (int p = 0; p < 4; ++p) {
            float v = acc[oc][p];
            #pragma unroll
            for (int m = 1; m < 64; m <<= 1) v += __shfl_xor(v, m, 64);
            acc[oc][p] = v;
        }

    __shared__ float red[4][96];
    __shared__ float h_ld[4 * 24];
    __shared__ float cls_ld[4 * 18];
    __shared__ float reg_ld[4 * 36];
    const int wave = tid >> 6, lane = tid & 63;
    if (lane == 0) {
        #pragma unroll
        for (int oc = 0; oc < 24; ++oc)
            #pragma unroll
            for (int p = 0; p < 4; ++p) red[wave][oc * 4 + p] = acc[oc][p];
    }
    __syncthreads();
    if (tid < 96) {
        float s = red[0][tid] + red[1][tid] + red[2][tid] + red[3][tid];
        int oc = tid >> 2, p = tid & 3;
        h_ld[p * 24 + oc] = fmaxf(s + brpn[oc], 0.f);
    }
    __syncthreads();
    if (tid < 216) {    // 4 pos * 54 outputs (18 cls + 36 reg)
        int p = tid / 54, o = tid % 54;
        const float* hv = h_ld + p * 24;
        if (o < 18) {
            float s = bc[o];
            const float* w = Wc + o * 24;
            #pragma unroll
            for (int c = 0; c < 24; ++c) s += w[c] * hv[c];
            cls_ld[p * 18 + o] = s;
            out[OFF_CLS + (y * 24 + xb + p) * 18 + o] = s;
        } else {
            int o2 = o - 18;
            float s = br[o2];
            const float* w = Wr + o2 * 24;
            #pragma unroll
            for (int c = 0; c < 24; ++c) s += w[c] * hv[c];
            reg_ld[p * 36 + o2] = s;
        }
    }
    __syncthreads();
    if (tid < 36) {     // 4 pos * 9 anchors
        #pragma clang fp contract(off)
        int p = tid / 9, k = tid % 9;
        int n = (y * 24 + xb + p) * 9 + k;
        float ax = anchors[4 * n], ay = anchors[4 * n + 1];
        float aw = anchors[4 * n + 2], ah = anchors[4 * n + 3];
        float tx = reg_ld[p * 36 + 4 * k],     ty = reg_ld[p * 36 + 4 * k + 1];
        float tw = reg_ld[p * 36 + 4 * k + 2], th = reg_ld[p * 36 + 4 * k + 3];
        float px = ax + aw * tx, py = ay + ah * ty;
        float pw = aw * expf(tw), ph = ah * expf(th);
        out[OFF_PROP + 4 * n]     = px;
        out[OFF_PROP + 4 * n + 1] = py;
        out[OFF_PROP + 4 * n + 2] = pw;
        out[OFF_PROP + 4 * n + 3] = ph;
        // geometric validity straight from anchors (exact: all values are
        // multiples of 0.5, f32 arithmetic identical to numpy reference)
        float gx0 = ax - 0.5f * (aw - 1.f);
        float gy0 = ay - 0.5f * (ah - 1.f);
        float gx1 = aw + gx0 - 1.f;
        float gy1 = ah + gy0 - 1.f;
        bool geo_ok = (gx0 >= 0.f) & (gy0 >= 0.f) & (gx1 < IMGW) & (gy1 < IMGW);
        float x0 = px - 0.5f * (pw - 1.f);
        float y0 = py - 0.5f * (ph - 1.f);
        float x1 = pw + x0 - 1.f;
        float y1 = ph + y0 - 1.f;
        x0 = fminf(fmaxf(x0, 0.f), IMGM1);
        x1 = fminf(fmaxf(x1, 0.f), IMGM1);
        y0 = fminf(fmaxf(y0, 0.f), IMGM1);
        y1 = fminf(fmaxf(y1, 0.f), IMGM1);
        float wsb = x1 - x0 + 1.f, hsb = y1 - y0 + 1.f;
        float c0 = cls_ld[p * 18 + 2 * k], c1 = cls_ld[p * 18 + 2 * k + 1];
        float mx = fmaxf(c0, c1);
        float e0 = expf(c0 - mx), e1 = expf(c1 - mx);
        float pr = e1 / (e0 + e1);
        boxes[n] = make_float4(x0, y0, x1, y1);
        probs[n] = pr;
        bool valid = geo_ok && (wsb >= MINSZ) && (hsb >= MINSZ);
        if (valid) {
            unsigned pos = atomicAdd(cnt, 1u);
            unsigned u = __float_as_uint(pr);
            unsigned enc = u ^ ((u >> 31) ? 0xFFFFFFFFu : 0x80000000u); // ascending in value
            vkeys[pos] = ((unsigned long long)(~enc) << 32) | (unsigned)n; // asc sort => desc prob, tie: idx asc
        }
    }
}

// ============ K2: bitonic sort of <=1024 valid keys (1 block) ============
__global__ __launch_bounds__(512) void k_sort(const unsigned long long* __restrict__ vkeys,
                                              const unsigned* __restrict__ cnt,
                                              int* __restrict__ sidx,
                                              float4* __restrict__ sbox,
                                              const float4* __restrict__ boxes) {
    __shared__ unsigned long long keys[1024];
    const int t = threadIdx.x;
    unsigned Mc = *cnt; unsigned M = Mc < (unsigned)MCAP ? Mc : (unsigned)MCAP;
    for (int i = t; i < 1024; i += 512) keys[i] = (i < (int)M) ? vkeys[i] : ~0ULL;
    __syncthreads();
    for (int k = 2; k <= 1024; k <<= 1) {
        for (int j = k >> 1; j > 0; j >>= 1) {
            int lo = t & (j - 1);
            int i = ((t ^ lo) << 1) | lo;
            int pa = i | j;
            bool up = (i & k) == 0;
            unsigned long long a = keys[i], b = keys[pa];
            if ((a > b) == up) { keys[i] = b; keys[pa] = a; }
            __syncthreads();
        }
    }
    for (int i = t; i < (int)M; i += 512) {
        int n = (int)(keys[i] & 0xFFFFFFFFu);
        sidx[i] = n;
        sbox[i] = boxes[n];
    }
}

// ============ K3: triangular IoU>thresh bitmask ============
__global__ __launch_bounds__(256) void k_mask(const float4* __restrict__ sbox,
                                              const unsigned* __restrict__ cnt,
                                              unsigned long long* __restrict__ mask) {
    __shared__ float4 sb[MCAP];
    const int t = threadIdx.x;
    for (int i = t; i < MCAP; i += 256) sb[i] = sbox[i];
    __syncthreads();
    unsigned Mc = *cnt; unsigned M = Mc < (unsigned)MCAP ? Mc : (unsigned)MCAP;
    int widx = blockIdx.x * 256 + t;
    if (widx >= TOTW) return;
    // decode triangular word index -> (row i, column group gw)
    int g = 0, base = 0;
    while (g < GCAP - 1) {
        int nb = base + 64 * (GCAP - g);
        if (widx < nb) break;
        base = nb; ++g;
    }
    int rem = widx - base;
    int r = rem / (GCAP - g);
    int gw = g + rem % (GCAP - g);
    int i = g * 64 + r;
    if (i >= (int)M) return;       // row never read
    {
        #pragma clang fp contract(off)
        float4 bi = sb[i];
        float ai = (bi.z - bi.x + 1.f) * (bi.w - bi.y + 1.f);
        unsigned long long w = 0;
        #pragma unroll 4
        for (int b = 0; b < 64; ++b) {
            int j = gw * 64 + b;
            if (j > i) {
                float4 bj = sb[j];
                float iw = fminf(bi.z, bj.z) - fmaxf(bi.x, bj.x) + 1.f;
                float ih = fminf(bi.w, bj.w) - fmaxf(bi.y, bj.y) + 1.f;
                iw = fmaxf(iw, 0.f); ih = fmaxf(ih, 0.f);
                float inter = iw * ih;
                float aj = (bj.z - bj.x + 1.f) * (bj.w - bj.y + 1.f);
                float iou = inter / (ai + aj - inter);
                if (iou > THRESH) w |= 1ULL << b;
            }
        }
        mask[widx] = w;
    }
}

// ============ K4: group-scalar greedy NMS + full output finalize ============
// Greedy pass restructured: per 64-item group, the in-group serial decisions
// run on wave-uniform scalars via v_readlane (no memory op on the critical
// path); cross-group suppression rows are ORed with independent (pipelined)
// LDS reads. Critical path ~13 groups x ~1k cycles vs 808 x ~300 before.
__global__ __launch_bounds__(1024) void k_nms(const unsigned long long* __restrict__ mask_g,
                                              const int* __restrict__ sidx_g,
                                              const unsigned* __restrict__ cnt,
                                              const float4* __restrict__ boxes,
                                              const float* __restrict__ probs,
                                              const int* __restrict__ labels,
                                              float* __restrict__ out) {
    __shared__ unsigned long long mk[TOTW];          // 52.5 KB
    __shared__ int sidx[MCAP];
    __shared__ unsigned long long keepm[81];         // keep bits in ORIGINAL index space
    __shared__ unsigned long long keeps[GCAP];       // keep bits in SORTED space
    const int t = threadIdx.x;
    unsigned Mc = *cnt; unsigned M = Mc < (unsigned)MCAP ? Mc : (unsigned)MCAP;
    for (int i = t; i < TOTW; i += 1024) mk[i] = mask_g[i];
    if (t < MCAP) sidx[t] = sidx_g[t];
    if (t < 81) keepm[t] = 0;
    if (t < GCAP) keeps[t] = 0;
    __syncthreads();
    if (t < 64) {                                    // wave 0: group-serial greedy pass
        const int lane = t;
        unsigned long long remv = 0;                 // lane w owns suppression word w
        const int ngroups = (int)((M + 63) >> 6);
        for (int g = 0; g < ngroups; ++g) {
            const int rowstride = GCAP - g;
            const int base_g = 64 * (GCAP * g - (g * (g - 1)) / 2);
            // lane r preloads the in-group (diagonal) word of row (g,r)
            unsigned long long diag = mk[base_g + lane * rowstride];
            unsigned dlo = (unsigned)diag, dhi = (unsigned)(diag >> 32);
            // current suppression word for this group, from lane g (uniform)
            unsigned slo = (unsigned)__builtin_amdgcn_readlane((int)(unsigned)remv, g);
            unsigned shi = (unsigned)__builtin_amdgcn_readlane((int)(unsigned)(remv >> 32), g);
            unsigned long long supp = ((unsigned long long)shi << 32) | slo;
            unsigned long long kw = 0;
            int nbits = (int)M - g * 64; if (nbits > 64) nbits = 64;
            for (int r = 0; r < nbits; ++r) {
                if (!((supp >> r) & 1ULL)) {
                    kw |= 1ULL << r;
                    unsigned rlo = (unsigned)__builtin_amdgcn_readlane((int)dlo, r);
                    unsigned rhi = (unsigned)__builtin_amdgcn_readlane((int)dhi, r);
                    supp |= ((unsigned long long)rhi << 32) | rlo;
                }
            }
            if (lane == 0) keeps[g] = kw;
            // cross-group suppression update (independent, pipelined LDS reads)
            if (lane > g && lane < GCAP) {
                const unsigned long long* rowp = &mk[base_g + (lane - g)];
                unsigned long long kwi = kw;
                while (kwi) {
                    int r = __ffsll((unsigned long long)kwi) - 1;
                    kwi &= kwi - 1;
                    remv |= rowp[r * rowstride];
                }
            }
        }
    }
    __syncthreads();
    if (t < (int)M) {
        if ((keeps[t >> 6] >> (t & 63)) & 1ULL) {
            int n = sidx[t];
            atomicOr(&keepm[n >> 6], 1ULL << (n & 63));
        }
    }
    __syncthreads();
    for (int n = t; n < NANC; n += 1024) {
        unsigned long long kb = (keepm[n >> 6] >> (n & 63)) & 1ULL;
        float kf = kb ? 1.f : 0.f;
        float4 b = boxes[n];
        float wsb = b.z - b.x + 1.f, hsb = b.w - b.y + 1.f;
        out[OFF_FILT + 4 * n]     = (b.x + 0.5f * (wsb - 1.f)) * kf;
        out[OFF_FILT + 4 * n + 1] = (b.y + 0.5f * (hsb - 1.f)) * kf;
        out[OFF_FILT + 4 * n + 2] = wsb * kf;
        out[OFF_FILT + 4 * n + 3] = hsb * kf;
        out[OFF_PK + n]  = probs[n] * kf;
        out[OFF_LBL + n] = kb ? (float)labels[n] : 0.f;
        out[OFF_KEEP + n] = kf;
    }
}

extern "C" void kernel_launch(void* const* d_in, const int* in_sizes, int n_in,
                              void* d_out, int out_size, void* d_ws, size_t ws_size,
                              hipStream_t stream) {
    const float* x        = (const float*)d_in[0];
    const int*   labels   = (const int*)d_in[1];
    const float* Wrpn     = (const float*)d_in[2];
    const float* brpn     = (const float*)d_in[3];
    const float* Wcls     = (const float*)d_in[4];
    const float* bcls     = (const float*)d_in[5];
    const float* Wreg     = (const float*)d_in[6];
    const float* breg     = (const float*)d_in[7];
    const float* anchors  = (const float*)d_in[8];
    float* out = (float*)d_out;
    char* ws = (char*)d_ws;

    float*  xt    = (float*)(ws + WS_XT);
    float*  Wt    = (float*)(ws + WS_WT);
    float4* boxes = (float4*)(ws + WS_BOX);
    float*  probs = (float*)(ws + WS_PROB);
    unsigned long long* vkeys = (unsigned long long*)(ws + WS_KEYS);
    int*    sidx  = (int*)(ws + WS_SIDX);
    float4* sbox  = (float4*)(ws + WS_SBOX);
    unsigned long long* mask = (unsigned long long*)(ws + WS_MASK);
    unsigned* cnt = (unsigned*)(ws + WS_CNT);

    k_prep<<<1584, 256, 0, stream>>>(x, Wrpn, xt, Wt, cnt);
    k_main<<<144, 256, 0, stream>>>(xt, Wt, brpn, Wcls, bcls, Wreg, breg,
                                    anchors, out, boxes, probs, vkeys, cnt);
    k_sort<<<1, 512, 0, stream>>>(vkeys, cnt, sidx, sbox, boxes);
    k_mask<<<27, 256, 0, stream>>>(sbox, cnt, mask);
    k_nms<<<1, 1024, 0, stream>>>(mask, sidx, cnt, boxes, probs, labels, out);
}

// Round 5
// 139.330 us; speedup vs baseline: 1.6256x; 1.2331x over previous
//
#include <hip/hip_runtime.h>
#include <hip/hip_bf16.h>
#include <math.h>

// ---------------- problem constants ----------------
#define NANC   5184        // 24*24*9
#define NPOS   576         // 24*24
#define CIN    512
#define MIDC   24
#define KANC   9
#define IMGW   384.0f
#define IMGM1  383.0f
#define MINSZ  16.0f
#define THRESH 0.7f

// d_out float offsets (outputs concatenated flat in return order)
#define OFF_PROP 0           // proposals  N*4
#define OFF_CLS  20736       // cls_out    N*2
#define OFF_FILT 31104       // filtered   N*4
#define OFF_PK   51840       // probs_kept N
#define OFF_LBL  57024       // labels_kept N (int -> float)
#define OFF_KEEP 62208       // keep       N (bool -> float)

// NMS capacity (geometric valid count is exactly 808)
#define MCAP 896
#define GCAP 14              // MCAP/64
#define TOTW (64 * (GCAP*(GCAP+1)/2))   // 6720 triangular u64 words

// ---------------- ws byte offsets ----------------
#define WS_XT    0            // 294912 f   (x transposed: [pos][ic])
#define WS_WT    1179648      // 110592 f   (W transposed: [oc][k][ic])
#define WS_BOX   1622016      // N float4   clipped boxes x0,y0,x1,y1
#define WS_PROB  1953792      // N f        softmax prob of class 1
#define WS_KEYS  2036736      // 1024 u64   sort keys of valid anchors
#define WS_SIDX  2044928      // 1024 i32   sorted orig indices
#define WS_SBOX  2049024      // MCAP float4 sorted boxes
#define WS_MASK  2063360      // TOTW u64   triangular IoU mask
#define WS_CNT   2117120      // u32        valid counter

// ============ K0: transpose x and W_rpn, zero counter ============
__global__ __launch_bounds__(256) void k_prep(const float* __restrict__ x,
                                              const float* __restrict__ W,
                                              float* __restrict__ xt,
                                              float* __restrict__ Wt,
                                              unsigned* cnt) {
    int tid = blockIdx.x * 256 + threadIdx.x;
    if (tid == 0) *cnt = 0;
    const int TOT = CIN * NPOS + MIDC * CIN * 9;   // 294912 + 110592
    for (int idx = tid; idx < TOT; idx += gridDim.x * 256) {
        if (idx < CIN * NPOS) {
            int pos = idx >> 9, ic = idx & 511;       // xt[pos*512+ic]
            xt[idx] = x[ic * NPOS + pos];
        } else {
            int k = idx - CIN * NPOS;                 // Wt[(oc*9+kk)*512+ic]
            int ic = k & 511; int t = k >> 9;
            int oc = t / 9, kk = t % 9;
            Wt[k] = W[(oc * CIN + ic) * 9 + kk];
        }
    }
}

// ============ K1: conv3x3+relu + heads + decode + score ============
// 144 blocks, each handles 4 consecutive positions in one row (24%4==0).
__global__ __launch_bounds__(256) void k_main(
        const float* __restrict__ xt, const float* __restrict__ Wt,
        const float* __restrict__ brpn,
        const float* __restrict__ Wc, const float* __restrict__ bc,
        const float* __restrict__ Wr, const float* __restrict__ br,
        const float* __restrict__ anchors,
        float* __restrict__ out, float4* __restrict__ boxes,
        float* __restrict__ probs, unsigned long long* __restrict__ vkeys,
        unsigned* __restrict__ cnt) {
    const int tid = threadIdx.x;
    const int y = blockIdx.x / 6;
    const int xb = (blockIdx.x % 6) * 4;

    float acc[24][4];
    #pragma unroll
    for (int oc = 0; oc < 24; ++oc)
        #pragma unroll
        for (int p = 0; p < 4; ++p) acc[oc][p] = 0.f;

    for (int half = 0; half < 2; ++half) {
        const int ic = tid + half * 256;
        float xw[3][6];
        #pragma unroll
        for (int r = 0; r < 3; ++r) {
            int yy = y - 1 + r;
            #pragma unroll
            for (int c = 0; c < 6; ++c) {
                int xx = xb - 1 + c;
                bool in = (yy >= 0) & (yy < 24) & (xx >= 0) & (xx < 24);
                xw[r][c] = in ? xt[(yy * 24 + xx) * CIN + ic] : 0.f;
            }
        }
        const float* wp = Wt + ic;
        #pragma unroll
        for (int oc = 0; oc < 24; ++oc) {
            #pragma unroll
            for (int kk = 0; kk < 9; ++kk) {
                const int r = kk / 3, c = kk % 3;
                float wv = wp[(oc * 9 + kk) * CIN];
                #pragma unroll
                for (int p = 0; p < 4; ++p)
                    acc[oc][p] += wv * xw[r][c + p];
            }
        }
    }
    // butterfly reduce across the 64-lane wave
    #pragma unroll
    for (int oc = 0; oc < 24; ++oc)
        #pragma unroll
        for (int p = 0; p < 4; ++p) {
            float v = acc[oc][p];
            #pragma unroll
            for (int m = 1; m < 64; m <<= 1) v += __shfl_xor(v, m, 64);
            acc[oc][p] = v;
        }

    __shared__ float red[4][96];
    __shared__ float h_ld[4 * 24];
    __shared__ float cls_ld[4 * 18];
    __shared__ float reg_ld[4 * 36];
    const int wave = tid >> 6, lane = tid & 63;
    if (lane == 0) {
        #pragma unroll
        for (int oc = 0; oc < 24; ++oc)
            #pragma unroll
            for (int p = 0; p < 4; ++p) red[wave][oc * 4 + p] = acc[oc][p];
    }
    __syncthreads();
    if (tid < 96) {
        float s = red[0][tid] + red[1][tid] + red[2][tid] + red[3][tid];
        int oc = tid >> 2, p = tid & 3;
        h_ld[p * 24 + oc] = fmaxf(s + brpn[oc], 0.f);
    }
    __syncthreads();
    if (tid < 216) {    // 4 pos * 54 outputs (18 cls + 36 reg)
        int p = tid / 54, o = tid % 54;
        const float* hv = h_ld + p * 24;
        if (o < 18) {
            float s = bc[o];
            const float* w = Wc + o * 24;
            #pragma unroll
            for (int c = 0; c < 24; ++c) s += w[c] * hv[c];
            cls_ld[p * 18 + o] = s;
            out[OFF_CLS + (y * 24 + xb + p) * 18 + o] = s;
        } else {
            int o2 = o - 18;
            float s = br[o2];
            const float* w = Wr + o2 * 24;
            #pragma unroll
            for (int c = 0; c < 24; ++c) s += w[c] * hv[c];
            reg_ld[p * 36 + o2] = s;
        }
    }
    __syncthreads();
    if (tid < 36) {     // 4 pos * 9 anchors
        #pragma clang fp contract(off)
        int p = tid / 9, k = tid % 9;
        int n = (y * 24 + xb + p) * 9 + k;
        float ax = anchors[4 * n], ay = anchors[4 * n + 1];
        float aw = anchors[4 * n + 2], ah = anchors[4 * n + 3];
        float tx = reg_ld[p * 36 + 4 * k],     ty = reg_ld[p * 36 + 4 * k + 1];
        float tw = reg_ld[p * 36 + 4 * k + 2], th = reg_ld[p * 36 + 4 * k + 3];
        float px = ax + aw * tx, py = ay + ah * ty;
        float pw = aw * expf(tw), ph = ah * expf(th);
        out[OFF_PROP + 4 * n]     = px;
        out[OFF_PROP + 4 * n + 1] = py;
        out[OFF_PROP + 4 * n + 2] = pw;
        out[OFF_PROP + 4 * n + 3] = ph;
        // geometric validity straight from anchors (exact: all values are
        // multiples of 0.5, f32 arithmetic identical to numpy reference)
        float gx0 = ax - 0.5f * (aw - 1.f);
        float gy0 = ay - 0.5f * (ah - 1.f);
        float gx1 = aw + gx0 - 1.f;
        float gy1 = ah + gy0 - 1.f;
        bool geo_ok = (gx0 >= 0.f) & (gy0 >= 0.f) & (gx1 < IMGW) & (gy1 < IMGW);
        float x0 = px - 0.5f * (pw - 1.f);
        float y0 = py - 0.5f * (ph - 1.f);
        float x1 = pw + x0 - 1.f;
        float y1 = ph + y0 - 1.f;
        x0 = fminf(fmaxf(x0, 0.f), IMGM1);
        x1 = fminf(fmaxf(x1, 0.f), IMGM1);
        y0 = fminf(fmaxf(y0, 0.f), IMGM1);
        y1 = fminf(fmaxf(y1, 0.f), IMGM1);
        float wsb = x1 - x0 + 1.f, hsb = y1 - y0 + 1.f;
        float c0 = cls_ld[p * 18 + 2 * k], c1 = cls_ld[p * 18 + 2 * k + 1];
        float mx = fmaxf(c0, c1);
        float e0 = expf(c0 - mx), e1 = expf(c1 - mx);
        float pr = e1 / (e0 + e1);
        boxes[n] = make_float4(x0, y0, x1, y1);
        probs[n] = pr;
        bool valid = geo_ok && (wsb >= MINSZ) && (hsb >= MINSZ);
        if (valid) {
            unsigned pos = atomicAdd(cnt, 1u);
            unsigned u = __float_as_uint(pr);
            unsigned enc = u ^ ((u >> 31) ? 0xFFFFFFFFu : 0x80000000u); // ascending in value
            vkeys[pos] = ((unsigned long long)(~enc) << 32) | (unsigned)n; // asc sort => desc prob, tie: idx asc
        }
    }
}

// ============ K2: bitonic sort of <=1024 valid keys (1 block) ============
__global__ __launch_bounds__(512) void k_sort(const unsigned long long* __restrict__ vkeys,
                                              const unsigned* __restrict__ cnt,
                                              int* __restrict__ sidx,
                                              float4* __restrict__ sbox,
                                              const float4* __restrict__ boxes) {
    __shared__ unsigned long long keys[1024];
    const int t = threadIdx.x;
    unsigned Mc = *cnt; unsigned M = Mc < (unsigned)MCAP ? Mc : (unsigned)MCAP;
    for (int i = t; i < 1024; i += 512) keys[i] = (i < (int)M) ? vkeys[i] : ~0ULL;
    __syncthreads();
    for (int k = 2; k <= 1024; k <<= 1) {
        for (int j = k >> 1; j > 0; j >>= 1) {
            int lo = t & (j - 1);
            int i = ((t ^ lo) << 1) | lo;
            int pa = i | j;
            bool up = (i & k) == 0;
            unsigned long long a = keys[i], b = keys[pa];
            if ((a > b) == up) { keys[i] = b; keys[pa] = a; }
            __syncthreads();
        }
    }
    for (int i = t; i < (int)M; i += 512) {
        int n = (int)(keys[i] & 0xFFFFFFFFu);
        sidx[i] = n;
        sbox[i] = boxes[n];
    }
}

// ============ K3: triangular IoU>thresh bitmask ============
__global__ __launch_bounds__(256) void k_mask(const float4* __restrict__ sbox,
                                              const unsigned* __restrict__ cnt,
                                              unsigned long long* __restrict__ mask) {
    __shared__ float4 sb[MCAP];
    const int t = threadIdx.x;
    for (int i = t; i < MCAP; i += 256) sb[i] = sbox[i];
    __syncthreads();
    unsigned Mc = *cnt; unsigned M = Mc < (unsigned)MCAP ? Mc : (unsigned)MCAP;
    int widx = blockIdx.x * 256 + t;
    if (widx >= TOTW) return;
    // decode triangular word index -> (row i, column group gw)
    int g = 0, base = 0;
    while (g < GCAP - 1) {
        int nb = base + 64 * (GCAP - g);
        if (widx < nb) break;
        base = nb; ++g;
    }
    int rem = widx - base;
    int r = rem / (GCAP - g);
    int gw = g + rem % (GCAP - g);
    int i = g * 64 + r;
    if (i >= (int)M) return;       // row never read
    {
        #pragma clang fp contract(off)
        float4 bi = sb[i];
        float ai = (bi.z - bi.x + 1.f) * (bi.w - bi.y + 1.f);
        unsigned long long w = 0;
        #pragma unroll 4
        for (int b = 0; b < 64; ++b) {
            int j = gw * 64 + b;
            if (j > i) {
                float4 bj = sb[j];
                float iw = fminf(bi.z, bj.z) - fmaxf(bi.x, bj.x) + 1.f;
                float ih = fminf(bi.w, bj.w) - fmaxf(bi.y, bj.y) + 1.f;
                iw = fmaxf(iw, 0.f); ih = fmaxf(ih, 0.f);
                float inter = iw * ih;
                float aj = (bj.z - bj.x + 1.f) * (bj.w - bj.y + 1.f);
                float iou = inter / (ai + aj - inter);
                if (iou > THRESH) w |= 1ULL << b;
            }
        }
        mask[widx] = w;
    }
}

// ============ K4: greedy NMS (nz-shortcut serial + parallel cross-group) ============
// In-group: only rows with nonzero in-group diag word can modify supp; the
// matrix is strictly upper-triangular, so iterating just those rows (ballot +
// ffs) and taking keep = ~supp_final is exactly the serial greedy result.
// Cross-group: wave h OR-reduces the kept rows' word h with one parallel
// vector LDS load + shfl tree (replaces 780 latency-serialized LDS reads).
__global__ __launch_bounds__(1024) void k_nms(const unsigned long long* __restrict__ mask_g,
                                              const int* __restrict__ sidx_g,
                                              const unsigned* __restrict__ cnt,
                                              const float4* __restrict__ boxes,
                                              const float* __restrict__ probs,
                                              const int* __restrict__ labels,
                                              float* __restrict__ out) {
    __shared__ unsigned long long mk[TOTW];          // 52.5 KB
    __shared__ int sidx[MCAP];
    __shared__ unsigned long long keepm[81];         // keep bits in ORIGINAL index space
    __shared__ unsigned long long keeps[GCAP];       // keep bits in SORTED space
    __shared__ unsigned long long suppw[GCAP];       // running suppression words
    const int t = threadIdx.x;
    unsigned Mc = *cnt; unsigned M = Mc < (unsigned)MCAP ? Mc : (unsigned)MCAP;
    for (int i = t; i < TOTW; i += 1024) mk[i] = mask_g[i];
    if (t < MCAP) sidx[t] = sidx_g[t];
    if (t < 81) keepm[t] = 0;
    if (t < GCAP) { keeps[t] = 0; suppw[t] = 0; }
    __syncthreads();
    const int wid = t >> 6, lane = t & 63;
    const int ngroups = (int)((M + 63) >> 6);
    for (int g = 0; g < ngroups; ++g) {
        const int rowstride = GCAP - g;
        const int base_g = 64 * (GCAP * g - (g * (g - 1)) / 2);
        int nbits = (int)M - g * 64; if (nbits > 64) nbits = 64;
        unsigned long long vmaskbits = (nbits < 64) ? ((1ULL << nbits) - 1ULL) : ~0ULL;
        if (wid == 0) {
            // lane r holds the in-group (diagonal) word of row (g,r)
            unsigned long long diag = mk[base_g + lane * rowstride];
            unsigned dlo = (unsigned)diag, dhi = (unsigned)(diag >> 32);
            unsigned long long supp = suppw[g];
            unsigned long long nz = __ballot(diag != 0ULL) & vmaskbits;
            while (nz) {
                int r = __ffsll(nz) - 1;
                nz &= nz - 1;
                if (!((supp >> r) & 1ULL)) {
                    unsigned rlo = (unsigned)__builtin_amdgcn_readlane((int)dlo, r);
                    unsigned rhi = (unsigned)__builtin_amdgcn_readlane((int)dhi, r);
                    supp |= ((unsigned long long)rhi << 32) | rlo;
                }
            }
            if (lane == 0) keeps[g] = ~supp & vmaskbits;
        }
        __syncthreads();
        // parallel cross-group suppression: wave h==wid updates word h (g<h<GCAP)
        if (wid > g && wid < GCAP) {
            unsigned long long kw = keeps[g];
            unsigned long long v = ((kw >> lane) & 1ULL)
                ? mk[base_g + lane * rowstride + (wid - g)] : 0ULL;
            unsigned vlo = (unsigned)v, vhi = (unsigned)(v >> 32);
            #pragma unroll
            for (int m = 1; m < 64; m <<= 1) {
                vlo |= __shfl_xor(vlo, m, 64);
                vhi |= __shfl_xor(vhi, m, 64);
            }
            if (lane == 0)
                suppw[wid] |= ((unsigned long long)vhi << 32) | vlo;
        }
        __syncthreads();
    }
    if (t < (int)M) {
        if ((keeps[t >> 6] >> (t & 63)) & 1ULL) {
            int n = sidx[t];
            atomicOr(&keepm[n >> 6], 1ULL << (n & 63));
        }
    }
    __syncthreads();
    for (int n = t; n < NANC; n += 1024) {
        unsigned long long kb = (keepm[n >> 6] >> (n & 63)) & 1ULL;
        float kf = kb ? 1.f : 0.f;
        float4 b = boxes[n];
        float wsb = b.z - b.x + 1.f, hsb = b.w - b.y + 1.f;
        out[OFF_FILT + 4 * n]     = (b.x + 0.5f * (wsb - 1.f)) * kf;
        out[OFF_FILT + 4 * n + 1] = (b.y + 0.5f * (hsb - 1.f)) * kf;
        out[OFF_FILT + 4 * n + 2] = wsb * kf;
        out[OFF_FILT + 4 * n + 3] = hsb * kf;
        out[OFF_PK + n]  = probs[n] * kf;
        out[OFF_LBL + n] = kb ? (float)labels[n] : 0.f;
        out[OFF_KEEP + n] = kf;
    }
}

extern "C" void kernel_launch(void* const* d_in, const int* in_sizes, int n_in,
                              void* d_out, int out_size, void* d_ws, size_t ws_size,
                              hipStream_t stream) {
    const float* x        = (const float*)d_in[0];
    const int*   labels   = (const int*)d_in[1];
    const float* Wrpn     = (const float*)d_in[2];
    const float* brpn     = (const float*)d_in[3];
    const float* Wcls     = (const float*)d_in[4];
    const float* bcls     = (const float*)d_in[5];
    const float* Wreg     = (const float*)d_in[6];
    const float* breg     = (const float*)d_in[7];
    const float* anchors  = (const float*)d_in[8];
    float* out = (float*)d_out;
    char* ws = (char*)d_ws;

    float*  xt    = (float*)(ws + WS_XT);
    float*  Wt    = (float*)(ws + WS_WT);
    float4* boxes = (float4*)(ws + WS_BOX);
    float*  probs = (float*)(ws + WS_PROB);
    unsigned long long* vkeys = (unsigned long long*)(ws + WS_KEYS);
    int*    sidx  = (int*)(ws + WS_SIDX);
    float4* sbox  = (float4*)(ws + WS_SBOX);
    unsigned long long* mask = (unsigned long long*)(ws + WS_MASK);
    unsigned* cnt = (unsigned*)(ws + WS_CNT);

    k_prep<<<1584, 256, 0, stream>>>(x, Wrpn, xt, Wt, cnt);
    k_main<<<144, 256, 0, stream>>>(xt, Wt, brpn, Wcls, bcls, Wreg, breg,
                                    anchors, out, boxes, probs, vkeys, cnt);
    k_sort<<<1, 512, 0, stream>>>(vkeys, cnt, sidx, sbox, boxes);
    k_mask<<<27, 256, 0, stream>>>(sbox, cnt, mask);
    k_nms<<<1, 1024, 0, stream>>>(mask, sidx, cnt, boxes, probs, labels, out);
}